// Round 3
// baseline (12643.671 us; speedup 1.0000x reference)
//
#include <hip/hip_runtime.h>
#include <cmath>

typedef unsigned short u16;
typedef unsigned long long u64;
typedef __attribute__((ext_vector_type(4))) float f32x4;
typedef __attribute__((ext_vector_type(8))) __bf16 bf16x8;
typedef unsigned short u16x4 __attribute__((ext_vector_type(4)));
typedef unsigned short u16x8 __attribute__((ext_vector_type(8)));

#define T_STEPS 512
#define NBLK 64
#define FINAL_OFF 33554432u  // 512*64*1024

// ---------------- workspace layout (bytes) ----------------
#define OFF_XR   0ull
#define OFF_XZ   (OFF_XR + 67108864ull)     // 512*64*1024 * 2B each
#define OFF_XH   (OFF_XZ + 67108864ull)
#define OFF_WXRT (OFF_XH + 67108864ull)     // 1024*1024*2B each
#define OFF_WXZT (OFF_WXRT + 2097152ull)
#define OFF_WXHT (OFF_WXZT + 2097152ull)
#define OFF_WHRT (OFF_WXHT + 2097152ull)
#define OFF_WHZT (OFF_WHRT + 2097152ull)
#define OFF_WHHT (OFF_WHZT + 2097152ull)
#define OFF_HBF  (OFF_WHHT + 2097152ull)    // 64*1024 bf16 (cross-block, coherent)
#define OFF_RHBF (OFF_HBF + 131072ull)      // 64*1024 bf16 (cross-block, coherent)
#define OFF_HF32 (OFF_RHBF + 131072ull)     // 64*1024 f32 (block-private)
#define OFF_BAR  (OFF_HF32 + 262144ull)     // 64 per-block flags, 128B apart
#define BAR_BYTES 65600ull

// ---------------- helpers ----------------
__device__ __forceinline__ u16 f2bf(float f) {
    unsigned u = __builtin_bit_cast(unsigned, f);
    unsigned r = (u + 0x7FFFu + ((u >> 16) & 1u)) >> 16;
    return (u16)r;
}
__device__ __forceinline__ float bf2f(u16 h) {
    unsigned u = ((unsigned)h) << 16;
    return __builtin_bit_cast(float, u);
}
struct U64x2 { u64 lo, hi; };
__device__ __forceinline__ bf16x8 mk(u64 lo, u64 hi) {
    U64x2 t{lo, hi};
    return __builtin_bit_cast(bf16x8, t);
}
#define MFMA16 __builtin_amdgcn_mfma_f32_16x16x32_bf16

// coherent (agent-scope) accesses, atomic flavor: used for flags + stores.
__device__ __forceinline__ void sta16(u16* p, u16 v) {
    __hip_atomic_store(p, v, __ATOMIC_RELAXED, __HIP_MEMORY_SCOPE_AGENT);
}

// Raw coherent loads (sc0|sc1 = bypass L1+L2, served by L3 coherence point).
// Same visibility semantics as a relaxed agent atomic load, but NOT
// atomic-flagged: issue is fire-and-forget, no compiler-inserted waits, so a
// 64-load stream pipelines fully. Completion is claimed by an explicit
// s_waitcnt vmcnt(0) + sched_barrier(0) (rule #18) before consumption.
#define LD_A(dst0, dst1, vo, base)                                   \
    asm volatile("global_load_dwordx2 %0, %2, %3 sc0 sc1\n\t"        \
                 "global_load_dwordx2 %1, %2, %3 offset:8 sc0 sc1"   \
                 : "=v"(dst0), "=v"(dst1)                            \
                 : "v"(vo), "s"(base))

__device__ __forceinline__ unsigned ld_u16_coh(u64 base, unsigned voff) {
    unsigned r;
    asm volatile("global_load_ushort %0, %1, %2 sc0 sc1"
                 : "=v"(r) : "v"(voff), "s"(base));
    return r;
}

// Distributed-flag grid barrier: each block stores a monotonically increasing
// phase number to its own 128B-padded flag; wave 0 polls all 64 flags with one
// 64-lane gather per iteration. vmcnt(0) before the flag store provides
// release; in-order issue after the poll provides acquire.
#define FLAG_STRIDE 32u  // 32 u32 = 128 bytes
__device__ __forceinline__ void arrive_wait(unsigned* flags, unsigned target) {
    asm volatile("s_waitcnt vmcnt(0)" ::: "memory");
    __syncthreads();
    if (threadIdx.x < 64) {
        if (threadIdx.x == 0)
            __hip_atomic_store(flags + (unsigned)blockIdx.x * FLAG_STRIDE, target,
                               __ATOMIC_RELAXED, __HIP_MEMORY_SCOPE_AGENT);
        const unsigned* fp = flags + threadIdx.x * FLAG_STRIDE;
        while (__hip_atomic_load(fp, __ATOMIC_RELAXED, __HIP_MEMORY_SCOPE_AGENT) < target)
            __builtin_amdgcn_s_sleep(1);
    }
    __syncthreads();
}

// ---------------- phase 0: transpose + fp32->bf16 convert, [K][N] -> [N][K] ----------------
__global__ __launch_bounds__(256) void transpose_cvt(
    const float* __restrict__ W0, const float* __restrict__ W1, const float* __restrict__ W2,
    const float* __restrict__ W3, const float* __restrict__ W4, const float* __restrict__ W5,
    u16* __restrict__ D0, u16* __restrict__ D1, u16* __restrict__ D2,
    u16* __restrict__ D3, u16* __restrict__ D4, u16* __restrict__ D5)
{
    const float* S[6] = {W0, W1, W2, W3, W4, W5};
    u16* D[6] = {D0, D1, D2, D3, D4, D5};
    int z = blockIdx.z;
    const float* W = S[z];
    u16* Dt = D[z];
    __shared__ float tile[32][33];
    int bx = blockIdx.x * 32, by = blockIdx.y * 32;
    int tx = threadIdx.x & 31, ty = threadIdx.x >> 5;
    for (int i = ty; i < 32; i += 8)
        tile[i][tx] = W[(size_t)(by + i) * 1024 + bx + tx];
    __syncthreads();
    for (int i = ty; i < 32; i += 8)
        Dt[(size_t)(bx + i) * 1024 + by + tx] = f2bf(tile[tx][i]);
}

// ---------------- phase 1: X @ Wx* + b -> bf16 projections ----------------
__global__ __launch_bounds__(256, 2) void proj_gemm(
    const float* __restrict__ X,
    const u16* __restrict__ Wt0, const u16* __restrict__ Wt1, const u16* __restrict__ Wt2,
    const float* __restrict__ b0, const float* __restrict__ b1, const float* __restrict__ b2,
    u16* __restrict__ P0, u16* __restrict__ P1, u16* __restrict__ P2)
{
    int z = blockIdx.z;
    const u16* Wt = (z == 0) ? Wt0 : (z == 1) ? Wt1 : Wt2;
    const float* bias = (z == 0) ? b0 : (z == 1) ? b1 : b2;
    u16* P = (z == 0) ? P0 : (z == 1) ? P1 : P2;

    __shared__ u16 Asm[128][72];
    __shared__ u16 Bsm[128][72];

    int tid = threadIdx.x, lane = tid & 63, w = tid >> 6;
    int m0 = blockIdx.y * 128, n0 = blockIdx.x * 128;
    int mw = (w >> 1) * 64, nw = (w & 1) * 64;
    int l15 = lane & 15, lq = lane >> 4;

    f32x4 zero = {0.f, 0.f, 0.f, 0.f};
    f32x4 acc[4][4];
    #pragma unroll
    for (int mi = 0; mi < 4; ++mi)
        #pragma unroll
        for (int nj = 0; nj < 4; ++nj) acc[mi][nj] = zero;

    for (int k0 = 0; k0 < 1024; k0 += 64) {
        #pragma unroll
        for (int i = 0; i < 8; ++i) {
            int flat = i * 256 + tid;
            int r = flat >> 4, c4 = flat & 15;
            float4 v = *(const float4*)(X + (size_t)(m0 + r) * 1024 + k0 + c4 * 4);
            u16x4 pk = {f2bf(v.x), f2bf(v.y), f2bf(v.z), f2bf(v.w)};
            *(u16x4*)&Asm[r][c4 * 4] = pk;
        }
        #pragma unroll
        for (int i = 0; i < 4; ++i) {
            int flat = i * 256 + tid;
            int n = flat >> 3, seg = flat & 7;
            *(u16x8*)&Bsm[n][seg * 8] = *(const u16x8*)(Wt + (size_t)(n0 + n) * 1024 + k0 + seg * 8);
        }
        __syncthreads();
        #pragma unroll
        for (int kk = 0; kk < 2; ++kk) {
            bf16x8 af[4], bg[4];
            #pragma unroll
            for (int mi = 0; mi < 4; ++mi)
                af[mi] = *(const bf16x8*)&Asm[mw + mi * 16 + l15][kk * 32 + lq * 8];
            #pragma unroll
            for (int nj = 0; nj < 4; ++nj)
                bg[nj] = *(const bf16x8*)&Bsm[nw + nj * 16 + l15][kk * 32 + lq * 8];
            #pragma unroll
            for (int mi = 0; mi < 4; ++mi)
                #pragma unroll
                for (int nj = 0; nj < 4; ++nj)
                    acc[mi][nj] = MFMA16(af[mi], bg[nj], acc[mi][nj], 0, 0, 0);
        }
        __syncthreads();
    }
    #pragma unroll
    for (int mi = 0; mi < 4; ++mi)
        #pragma unroll
        for (int nj = 0; nj < 4; ++nj)
            #pragma unroll
            for (int r = 0; r < 4; ++r) {
                int m = m0 + mw + mi * 16 + lq * 4 + r;
                int n = n0 + nw + nj * 16 + l15;
                float v = acc[mi][nj][r] + bias[n];
                P[(size_t)m * 1024 + n] = f2bf(v);
            }
}

// ---------------- phase 2: persistent recurrent kernel ----------------
// 64 blocks x 256 thr (4 waves, 1 wave/SIMD). Block b owns a 16-col stripe.
// A-operand (h / R*h) is prefetched per stage as 64 raw sc0|sc1 loads into
// registers (one L3 latency exposure), then consumed from registers against
// LDS-resident Whr/Whz (swizzled) and L2-hot Whh.
__global__ __launch_bounds__(256, 1) void gru_rec(
    const u16* __restrict__ XR, const u16* __restrict__ XZ, const u16* __restrict__ XH,
    const u16* __restrict__ Whrt, const u16* __restrict__ Whzt, const u16* __restrict__ Whht,
    const float* __restrict__ state,
    u16* __restrict__ hbf, u16* __restrict__ rhbf, float* __restrict__ hf32,
    unsigned* __restrict__ bar, float* __restrict__ out)
{
    __shared__ u16 Wsm[32 * 1024];  // rows 0-15: Whr slice; 16-31: Whz slice

    const int b = blockIdx.x, tid = threadIdx.x;
    const int lane = tid & 63, mi = tid >> 6;
    const int n15 = lane & 15, q = lane >> 4;
    const int k7 = n15 & 7;
    const int colg = 16 * b + n15;
    const int rowA = mi * 16 + n15;

    // fill LDS weight slices (swizzled 16B chunks: phys = chunk ^ (row&7))
    {
        int row = tid >> 3, seg = tid & 7;
        const u16* src = (row < 16) ? (Whrt + (size_t)(16 * b + row) * 1024)
                                    : (Whzt + (size_t)(16 * b + row - 16) * 1024);
        #pragma unroll
        for (int v = 0; v < 16; ++v) {
            int chunk = seg * 16 + v;
            int phys = chunk ^ (row & 7);
            *(u16x8*)&Wsm[row * 1024 + phys * 8] = *(const u16x8*)(src + chunk * 8);
        }
    }
    // init h: block writes its own 16-col stripe
    for (int i = tid; i < 1024; i += 256) {
        int row = i >> 4, c = i & 15;
        int idx = row * 1024 + 16 * b + c;
        float v = state[idx];
        hf32[idx] = v;              // private
        sta16(hbf + idx, f2bf(v));  // shared
    }
    arrive_wait(bar, 1);  // init phase

    const u64 hb64 = (u64)hbf;
    const u64 rb64 = (u64)rhbf;
    const unsigned vbA = (unsigned)(rowA * 2048 + q * 16);  // A-fragment byte base
    const u16* bp2 = Whht + (size_t)colg * 1024 + q * 8;

    for (int t = 0; t < T_STEPS; ++t) {
        f32x4 zreg;
        // ---------------- stage 1: R,Z; write rhbf = R*h ----------------
        {
            // early loads (consumed after the MFMA loop)
            u16 xr16[4], xz16[4];
            unsigned hv[4];
            #pragma unroll
            for (int r = 0; r < 4; ++r) {
                int idx = (mi * 16 + q * 4 + r) * 1024 + colg;
                size_t xoff = (size_t)t * 65536 + idx;
                xr16[r] = XR[xoff];
                xz16[r] = XZ[xoff];
                hv[r] = ld_u16_coh(hb64, (unsigned)(idx * 2));
            }
            // prefetch the full A stream: 64 raw coherent loads, fully pipelined
            u64 a0[32], a1[32];
            #pragma unroll
            for (int i = 0; i < 32; ++i)
                LD_A(a0[i], a1[i], vbA + i * 64, hb64);
            asm volatile("s_waitcnt vmcnt(0)" ::: "memory");
            __builtin_amdgcn_sched_barrier(0);

            f32x4 aRa = {0,0,0,0}, aRb = {0,0,0,0}, aZa = {0,0,0,0}, aZb = {0,0,0,0};
            #pragma unroll
            for (int kb = 0; kb < 32; ++kb) {
                bf16x8 a = mk(a0[kb], a1[kb]);
                int ph = ((kb * 4 + q) ^ k7) * 8;
                bf16x8 br = *(const bf16x8*)&Wsm[n15 * 1024 + ph];
                bf16x8 bz = *(const bf16x8*)&Wsm[(16 + n15) * 1024 + ph];
                if (kb & 1) { aRb = MFMA16(a, br, aRb, 0, 0, 0); aZb = MFMA16(a, bz, aZb, 0, 0, 0); }
                else        { aRa = MFMA16(a, br, aRa, 0, 0, 0); aZa = MFMA16(a, bz, aZa, 0, 0, 0); }
            }
            f32x4 accR = aRa + aRb, accZ = aZa + aZb;
            #pragma unroll
            for (int r = 0; r < 4; ++r) {
                int idx = (mi * 16 + q * 4 + r) * 1024 + colg;
                float rpre = accR[r] + bf2f(xr16[r]);
                float zpre = accZ[r] + bf2f(xz16[r]);
                float R = 1.f / (1.f + __expf(-rpre));
                zreg[r] = 1.f / (1.f + __expf(-zpre));
                sta16(rhbf + idx, f2bf(R * bf2f((u16)hv[r])));
            }
        }
        arrive_wait(bar, 2 + 2 * t);
        // ---------------- stage 2: Hhat = tanh(Xh + (R*h)@Whh); blend ----------------
        {
            u16 xh16[4];
            float hprev[4];
            #pragma unroll
            for (int r = 0; r < 4; ++r) {
                int idx = (mi * 16 + q * 4 + r) * 1024 + colg;
                xh16[r] = XH[(size_t)t * 65536 + idx];
                hprev[r] = hf32[idx];  // private, L1/L2-hot
            }
            // prefetch full A stream (R*h) + first B fragments
            u64 a0[32], a1[32];
            #pragma unroll
            for (int i = 0; i < 32; ++i)
                LD_A(a0[i], a1[i], vbA + i * 64, rb64);
            bf16x8 bbuf[4];
            #pragma unroll
            for (int i = 0; i < 4; ++i) bbuf[i] = *(const bf16x8*)(bp2 + i * 32);
            asm volatile("s_waitcnt vmcnt(0)" ::: "memory");
            __builtin_amdgcn_sched_barrier(0);

            f32x4 ca = {0,0,0,0}, cb = {0,0,0,0};
            #pragma unroll
            for (int kb = 0; kb < 32; ++kb) {
                bf16x8 a = mk(a0[kb], a1[kb]);
                bf16x8 bb = bbuf[kb & 3];
                if (kb < 28) bbuf[kb & 3] = *(const bf16x8*)(bp2 + (size_t)(kb + 4) * 32);
                if (kb & 1) cb = MFMA16(a, bb, cb, 0, 0, 0);
                else        ca = MFMA16(a, bb, ca, 0, 0, 0);
            }
            f32x4 acc = ca + cb;
            #pragma unroll
            for (int r = 0; r < 4; ++r) {
                int idx = (mi * 16 + q * 4 + r) * 1024 + colg;
                size_t xoff = (size_t)t * 65536 + idx;
                float pre = acc[r] + bf2f(xh16[r]);
                float ax = fabsf(pre);
                float e = __expf(-2.f * ax);
                float th = (1.f - e) / (1.f + e);
                float hh = (pre < 0.f) ? -th : th;
                float hn = zreg[r] * hprev[r] + (1.f - zreg[r]) * hh;
                out[xoff] = hn;                 // plain (write-once, lazy writeback)
                hf32[idx] = hn;                 // private
                sta16(hbf + idx, f2bf(hn));     // shared
                if (t == T_STEPS - 1) out[FINAL_OFF + idx] = hn;
            }
        }
        if (t != T_STEPS - 1)
            arrive_wait(bar, 3 + 2 * t);
        // last step: no consumer of hbf; kernel-exit flush covers 'out'
    }
}

// ---------------- launch ----------------
extern "C" void kernel_launch(void* const* d_in, const int* in_sizes, int n_in,
                              void* d_out, int out_size, void* d_ws, size_t ws_size,
                              hipStream_t stream) {
    (void)in_sizes; (void)n_in; (void)out_size; (void)ws_size;
    const float* X     = (const float*)d_in[0];
    const float* state = (const float*)d_in[1];
    const float* Wxr   = (const float*)d_in[2];
    const float* Whr   = (const float*)d_in[3];
    const float* br    = (const float*)d_in[4];
    const float* Wxz   = (const float*)d_in[5];
    const float* Whz   = (const float*)d_in[6];
    const float* bz    = (const float*)d_in[7];
    const float* Wxh   = (const float*)d_in[8];
    const float* Whh   = (const float*)d_in[9];
    const float* bh    = (const float*)d_in[10];
    float* out = (float*)d_out;
    char* ws = (char*)d_ws;

    u16* XR   = (u16*)(ws + OFF_XR);
    u16* XZ   = (u16*)(ws + OFF_XZ);
    u16* XH   = (u16*)(ws + OFF_XH);
    u16* WXRT = (u16*)(ws + OFF_WXRT);
    u16* WXZT = (u16*)(ws + OFF_WXZT);
    u16* WXHT = (u16*)(ws + OFF_WXHT);
    u16* WHRT = (u16*)(ws + OFF_WHRT);
    u16* WHZT = (u16*)(ws + OFF_WHZT);
    u16* WHHT = (u16*)(ws + OFF_WHHT);
    u16* HBF  = (u16*)(ws + OFF_HBF);
    u16* RHBF = (u16*)(ws + OFF_RHBF);
    float* HF32 = (float*)(ws + OFF_HF32);
    unsigned* BAR = (unsigned*)(ws + OFF_BAR);

    hipMemsetAsync(BAR, 0, BAR_BYTES, stream);

    transpose_cvt<<<dim3(32, 32, 6), 256, 0, stream>>>(
        Wxr, Wxz, Wxh, Whr, Whz, Whh,
        WXRT, WXZT, WXHT, WHRT, WHZT, WHHT);

    proj_gemm<<<dim3(8, 256, 3), 256, 0, stream>>>(
        X, WXRT, WXZT, WXHT, br, bz, bh, XR, XZ, XH);

    gru_rec<<<dim3(NBLK), 256, 0, stream>>>(
        XR, XZ, XH, WHRT, WHZT, WHHT, state,
        HBF, RHBF, HF32, BAR, out);
}

// Round 5
// 7534.563 us; speedup vs baseline: 1.6781x; 1.6781x over previous
//
#include <hip/hip_runtime.h>
#include <cmath>

typedef unsigned short u16;
typedef unsigned long long u64;
typedef __attribute__((ext_vector_type(4))) float f32x4;
typedef __attribute__((ext_vector_type(8))) __bf16 bf16x8;
typedef unsigned short u16x4 __attribute__((ext_vector_type(4)));
typedef unsigned short u16x8 __attribute__((ext_vector_type(8)));

#define T_STEPS 512
#define NBLK 64
#define FINAL_OFF 33554432u  // 512*64*1024

// ---------------- workspace layout (bytes) ----------------
#define OFF_XR   0ull
#define OFF_XZ   (OFF_XR + 67108864ull)     // 512*64*1024 * 2B each
#define OFF_XH   (OFF_XZ + 67108864ull)
#define OFF_WXRT (OFF_XH + 67108864ull)     // 1024*1024*2B each
#define OFF_WXZT (OFF_WXRT + 2097152ull)
#define OFF_WXHT (OFF_WXZT + 2097152ull)
#define OFF_WHRT (OFF_WXHT + 2097152ull)
#define OFF_WHZT (OFF_WHRT + 2097152ull)
#define OFF_WHHT (OFF_WHZT + 2097152ull)
#define OFF_HBF  (OFF_WHHT + 2097152ull)    // 64*1024 bf16 (cross-block, coherent)
#define OFF_RHBF (OFF_HBF + 131072ull)      // 64*1024 bf16 (cross-block, coherent)
#define OFF_HF32 (OFF_RHBF + 131072ull)     // (unused this version)
#define OFF_BAR  (OFF_HF32 + 262144ull)     // 64 per-block flags, 128B apart
#define BAR_BYTES 65600ull

// ---------------- helpers ----------------
__device__ __forceinline__ u16 f2bf(float f) {
    unsigned u = __builtin_bit_cast(unsigned, f);
    unsigned r = (u + 0x7FFFu + ((u >> 16) & 1u)) >> 16;
    return (u16)r;
}
__device__ __forceinline__ float bf2f(u16 h) {
    unsigned u = ((unsigned)h) << 16;
    return __builtin_bit_cast(float, u);
}
#define MFMA16 __builtin_amdgcn_mfma_f32_16x16x32_bf16

// coherent (agent-scope) atomic accesses: flags + cross-block data stores.
__device__ __forceinline__ void sta16(u16* p, u16 v) {
    __hip_atomic_store(p, v, __ATOMIC_RELAXED, __HIP_MEMORY_SCOPE_AGENT);
}
__device__ __forceinline__ void sta32(unsigned* p, unsigned v) {
    __hip_atomic_store(p, v, __ATOMIC_RELAXED, __HIP_MEMORY_SCOPE_AGENT);
}
__device__ __forceinline__ unsigned lda32(const unsigned* p) {
    return __hip_atomic_load(p, __ATOMIC_RELAXED, __HIP_MEMORY_SCOPE_AGENT);
}

// Raw coherent 16B load (sc0|sc1): same visibility as relaxed agent atomic,
// fire-and-forget issue; completion claimed by explicit vmcnt(0)+sched_barrier.
#define LD_A4(dst, vo, base)                                          \
    asm volatile("global_load_dwordx4 %0, %1, %2 sc0 sc1"             \
                 : "=v"(dst) : "v"(vo), "s"(base))

#define FLAG_STRIDE 32u  // 32 u32 = 128 bytes per flag

// ---------------- phase 0: transpose + fp32->bf16 convert, [K][N] -> [N][K] ----------------
__global__ __launch_bounds__(256) void transpose_cvt(
    const float* __restrict__ W0, const float* __restrict__ W1, const float* __restrict__ W2,
    const float* __restrict__ W3, const float* __restrict__ W4, const float* __restrict__ W5,
    u16* __restrict__ D0, u16* __restrict__ D1, u16* __restrict__ D2,
    u16* __restrict__ D3, u16* __restrict__ D4, u16* __restrict__ D5)
{
    const float* S[6] = {W0, W1, W2, W3, W4, W5};
    u16* D[6] = {D0, D1, D2, D3, D4, D5};
    int z = blockIdx.z;
    const float* W = S[z];
    u16* Dt = D[z];
    __shared__ float tile[32][33];
    int bx = blockIdx.x * 32, by = blockIdx.y * 32;
    int tx = threadIdx.x & 31, ty = threadIdx.x >> 5;
    for (int i = ty; i < 32; i += 8)
        tile[i][tx] = W[(size_t)(by + i) * 1024 + bx + tx];
    __syncthreads();
    for (int i = ty; i < 32; i += 8)
        Dt[(size_t)(bx + i) * 1024 + by + tx] = f2bf(tile[tx][i]);
}

// ---------------- phase 1: X @ Wx* + b -> bf16 projections ----------------
__global__ __launch_bounds__(256, 2) void proj_gemm(
    const float* __restrict__ X,
    const u16* __restrict__ Wt0, const u16* __restrict__ Wt1, const u16* __restrict__ Wt2,
    const float* __restrict__ b0, const float* __restrict__ b1, const float* __restrict__ b2,
    u16* __restrict__ P0, u16* __restrict__ P1, u16* __restrict__ P2)
{
    int z = blockIdx.z;
    const u16* Wt = (z == 0) ? Wt0 : (z == 1) ? Wt1 : Wt2;
    const float* bias = (z == 0) ? b0 : (z == 1) ? b1 : b2;
    u16* P = (z == 0) ? P0 : (z == 1) ? P1 : P2;

    __shared__ u16 Asm[128][72];
    __shared__ u16 Bsm[128][72];

    int tid = threadIdx.x, lane = tid & 63, w = tid >> 6;
    int m0 = blockIdx.y * 128, n0 = blockIdx.x * 128;
    int mw = (w >> 1) * 64, nw = (w & 1) * 64;
    int l15 = lane & 15, lq = lane >> 4;

    f32x4 zero = {0.f, 0.f, 0.f, 0.f};
    f32x4 acc[4][4];
    #pragma unroll
    for (int mi = 0; mi < 4; ++mi)
        #pragma unroll
        for (int nj = 0; nj < 4; ++nj) acc[mi][nj] = zero;

    for (int k0 = 0; k0 < 1024; k0 += 64) {
        #pragma unroll
        for (int i = 0; i < 8; ++i) {
            int flat = i * 256 + tid;
            int r = flat >> 4, c4 = flat & 15;
            float4 v = *(const float4*)(X + (size_t)(m0 + r) * 1024 + k0 + c4 * 4);
            u16x4 pk = {f2bf(v.x), f2bf(v.y), f2bf(v.z), f2bf(v.w)};
            *(u16x4*)&Asm[r][c4 * 4] = pk;
        }
        #pragma unroll
        for (int i = 0; i < 4; ++i) {
            int flat = i * 256 + tid;
            int n = flat >> 3, seg = flat & 7;
            *(u16x8*)&Bsm[n][seg * 8] = *(const u16x8*)(Wt + (size_t)(n0 + n) * 1024 + k0 + seg * 8);
        }
        __syncthreads();
        #pragma unroll
        for (int kk = 0; kk < 2; ++kk) {
            bf16x8 af[4], bg[4];
            #pragma unroll
            for (int mi = 0; mi < 4; ++mi)
                af[mi] = *(const bf16x8*)&Asm[mw + mi * 16 + l15][kk * 32 + lq * 8];
            #pragma unroll
            for (int nj = 0; nj < 4; ++nj)
                bg[nj] = *(const bf16x8*)&Bsm[nw + nj * 16 + l15][kk * 32 + lq * 8];
            #pragma unroll
            for (int mi = 0; mi < 4; ++mi)
                #pragma unroll
                for (int nj = 0; nj < 4; ++nj)
                    acc[mi][nj] = MFMA16(af[mi], bg[nj], acc[mi][nj], 0, 0, 0);
        }
        __syncthreads();
    }
    #pragma unroll
    for (int mi = 0; mi < 4; ++mi)
        #pragma unroll
        for (int nj = 0; nj < 4; ++nj)
            #pragma unroll
            for (int r = 0; r < 4; ++r) {
                int m = m0 + mw + mi * 16 + lq * 4 + r;
                int n = n0 + nw + nj * 16 + l15;
                float v = acc[mi][nj][r] + bias[n];
                P[(size_t)m * 1024 + n] = f2bf(v);
            }
}

// ---------------- phase 2: persistent recurrent kernel, DATAFLOW sync ----------------
// 64 blocks x 256 thr. Block b owns 16-col stripe [16b,16b+16) for R,Z,H.
// No grid barriers: per-block monotonic publish flag; consumers gate per
// 32-col k-pair on the two producer blocks' flags, polled via one 64-lane
// gather + ballot (refreshes readiness of all 64 producers per L3 round trip),
// throttled by s_sleep in the spin. Flag protocol: init->1; stage1(t)->2t+2;
// stage2(t)->2t+3. Stage1(t) consumes hbf gated on flag>=2t+1; stage2(t)
// consumes rhbf gated on flag>=2t+2. Release: vmcnt(0) drain (loads AND
// stores) + __syncthreads before each publish => flag>=N implies that block
// finished both reading and writing everything pre-N (WAR-safe on the
// single-buffered hbf/rhbf). Rotated consumption order breaks same-line
// convergence at the coherence point. h carried in registers across steps.
__global__ __launch_bounds__(256, 1) void gru_rec(
    const u16* __restrict__ XR, const u16* __restrict__ XZ, const u16* __restrict__ XH,
    const u16* __restrict__ Whrt, const u16* __restrict__ Whzt, const u16* __restrict__ Whht,
    const float* __restrict__ state,
    u16* __restrict__ hbf, u16* __restrict__ rhbf,
    unsigned* __restrict__ bar, float* __restrict__ out)
{
    __shared__ u16 Wsm[48 * 1024];  // rows 0-15 Whr, 16-31 Whz, 32-47 Whh (96 KB)

    const int b = blockIdx.x, tid = threadIdx.x;
    const int lane = tid & 63, mi = tid >> 6;
    const int n15 = lane & 15, q = lane >> 4;
    const int k7 = n15 & 7;
    const int colg = 16 * b + n15;
    const int rowA = mi * 16 + n15;
    const int rot = ((b >> 1) + ((b & 1) << 4)) & 31;  // per-block start pair
    const u64 own_bit = 1ull << b;

    // fill LDS weight slices (swizzled 16B chunks: phys = chunk ^ (row&7))
    {
        int r0 = tid >> 3, seg = tid & 7;
        #pragma unroll
        for (int pass = 0; pass < 2; ++pass) {
            int row = pass * 32 + r0;
            if (row < 48) {
                const u16* src = (row < 16) ? (Whrt + (size_t)(16 * b + row) * 1024)
                               : (row < 32) ? (Whzt + (size_t)(16 * b + row - 16) * 1024)
                                            : (Whht + (size_t)(16 * b + row - 32) * 1024);
                #pragma unroll
                for (int v = 0; v < 16; ++v) {
                    int chunk = seg * 16 + v;
                    int phys = chunk ^ (row & 7);
                    *(u16x8*)&Wsm[row * 1024 + phys * 8] = *(const u16x8*)(src + chunk * 8);
                }
            }
        }
    }
    // init h: own 16-col stripe -> registers (f32 carry) + hbf (bf16, shared)
    f32x4 hcar;
    #pragma unroll
    for (int r = 0; r < 4; ++r) {
        int idx = (mi * 16 + q * 4 + r) * 1024 + colg;
        float v = state[idx];
        hcar[r] = v;
        sta16(hbf + idx, f2bf(v));
    }
    // publish init (flag = 1)
    asm volatile("s_waitcnt vmcnt(0)" ::: "memory");
    __syncthreads();
    if (tid == 0) sta32(bar + (unsigned)b * FLAG_STRIDE, 1u);

    const u64 hb64 = (u64)hbf;
    const u64 rb64 = (u64)rhbf;
    const unsigned vbA = (unsigned)(rowA * 2048 + q * 16);  // A-fragment byte base
    const unsigned* fp = bar + (unsigned)lane * FLAG_STRIDE;  // lane l -> block l's flag

    for (int t = 0; t < T_STEPS; ++t) {
        f32x4 zreg;
        // ---------------- stage 1: R,Z; write rhbf = R*h ----------------
        {
            u16 xr16[4], xz16[4];
            #pragma unroll
            for (int r = 0; r < 4; ++r) {
                size_t xoff = (size_t)t * 65536 + (mi * 16 + q * 4 + r) * 1024 + colg;
                xr16[r] = XR[xoff];
                xz16[r] = XZ[xoff];
            }
            // dataflow consume: issue A-load for each k-pair as its producers arrive
            f32x4 a[32];
            const unsigned T1 = 2u * t + 1u;
            u64 rdy = __ballot(lda32(fp) >= T1) | own_bit;  // fast path: one gather
            #pragma unroll
            for (int i = 0; i < 32; ++i) {
                int kb = (i + rot) & 31;
                u64 need = 3ull << (2 * kb);
                while ((rdy & need) != need) {
                    __builtin_amdgcn_s_sleep(1);
                    rdy = __ballot(lda32(fp) >= T1) | own_bit;
                }
                LD_A4(a[i], vbA + kb * 64, hb64);
            }
            asm volatile("s_waitcnt vmcnt(0)" ::: "memory");
            __builtin_amdgcn_sched_barrier(0);

            f32x4 aRa = {0,0,0,0}, aRb = {0,0,0,0}, aZa = {0,0,0,0}, aZb = {0,0,0,0};
            #pragma unroll
            for (int i = 0; i < 32; ++i) {
                int kb = (i + rot) & 31;
                bf16x8 av = __builtin_bit_cast(bf16x8, a[i]);
                int ph = ((kb * 4 + q) ^ k7) * 8;
                bf16x8 br = *(const bf16x8*)&Wsm[n15 * 1024 + ph];
                bf16x8 bz = *(const bf16x8*)&Wsm[(16 + n15) * 1024 + ph];
                if (i & 1) { aRb = MFMA16(av, br, aRb, 0, 0, 0); aZb = MFMA16(av, bz, aZb, 0, 0, 0); }
                else       { aRa = MFMA16(av, br, aRa, 0, 0, 0); aZa = MFMA16(av, bz, aZa, 0, 0, 0); }
            }
            f32x4 accR = aRa + aRb, accZ = aZa + aZb;
            #pragma unroll
            for (int r = 0; r < 4; ++r) {
                int idx = (mi * 16 + q * 4 + r) * 1024 + colg;
                float rpre = accR[r] + bf2f(xr16[r]);
                float zpre = accZ[r] + bf2f(xz16[r]);
                float R = 1.f / (1.f + __expf(-rpre));
                zreg[r] = 1.f / (1.f + __expf(-zpre));
                sta16(rhbf + idx, f2bf(R * hcar[r]));
            }
            // publish stage 1 (flag = 2t+2)
            asm volatile("s_waitcnt vmcnt(0)" ::: "memory");
            __syncthreads();
            if (tid == 0) sta32(bar + (unsigned)b * FLAG_STRIDE, 2u * t + 2u);
        }
        // ---------------- stage 2: Hhat = tanh(Xh + (R*h)@Whh); blend ----------------
        {
            u16 xh16[4];
            #pragma unroll
            for (int r = 0; r < 4; ++r) {
                size_t xoff = (size_t)t * 65536 + (mi * 16 + q * 4 + r) * 1024 + colg;
                xh16[r] = XH[xoff];
            }
            f32x4 a[32];
            const unsigned T2 = 2u * t + 2u;
            u64 rdy = __ballot(lda32(fp) >= T2) | own_bit;  // fast path: one gather
            #pragma unroll
            for (int i = 0; i < 32; ++i) {
                int kb = (i + rot) & 31;
                u64 need = 3ull << (2 * kb);
                while ((rdy & need) != need) {
                    __builtin_amdgcn_s_sleep(1);
                    rdy = __ballot(lda32(fp) >= T2) | own_bit;
                }
                LD_A4(a[i], vbA + kb * 64, rb64);
            }
            asm volatile("s_waitcnt vmcnt(0)" ::: "memory");
            __builtin_amdgcn_sched_barrier(0);

            f32x4 ca = {0,0,0,0}, cb = {0,0,0,0};
            #pragma unroll
            for (int i = 0; i < 32; ++i) {
                int kb = (i + rot) & 31;
                bf16x8 av = __builtin_bit_cast(bf16x8, a[i]);
                int ph = ((kb * 4 + q) ^ k7) * 8;
                bf16x8 bh = *(const bf16x8*)&Wsm[(32 + n15) * 1024 + ph];
                if (i & 1) cb = MFMA16(av, bh, cb, 0, 0, 0);
                else       ca = MFMA16(av, bh, ca, 0, 0, 0);
            }
            f32x4 acc = ca + cb;
            float hn4[4];
            #pragma unroll
            for (int r = 0; r < 4; ++r) {
                int idx = (mi * 16 + q * 4 + r) * 1024 + colg;
                float pre = acc[r] + bf2f(xh16[r]);
                float ax = fabsf(pre);
                float e = __expf(-2.f * ax);
                float th = (1.f - e) / (1.f + e);
                float hh = (pre < 0.f) ? -th : th;
                float hn = zreg[r] * hcar[r] + (1.f - zreg[r]) * hh;
                hn4[r] = hn;
                hcar[r] = hn;
                sta16(hbf + idx, f2bf(hn));     // shared (coherent)
            }
            if (t != T_STEPS - 1) {
                // publish stage 2 (flag = 2t+3) BEFORE the out stores (out is
                // write-once, consumed only at kernel end; keeps HBM stores
                // off the publish critical path)
                asm volatile("s_waitcnt vmcnt(0)" ::: "memory");
                __syncthreads();
                if (tid == 0) sta32(bar + (unsigned)b * FLAG_STRIDE, 2u * t + 3u);
            }
            #pragma unroll
            for (int r = 0; r < 4; ++r) {
                int idx = (mi * 16 + q * 4 + r) * 1024 + colg;
                size_t xoff = (size_t)t * 65536 + idx;
                out[xoff] = hn4[r];
                if (t == T_STEPS - 1) out[FINAL_OFF + idx] = hn4[r];
            }
        }
    }
}

// ---------------- launch ----------------
extern "C" void kernel_launch(void* const* d_in, const int* in_sizes, int n_in,
                              void* d_out, int out_size, void* d_ws, size_t ws_size,
                              hipStream_t stream) {
    (void)in_sizes; (void)n_in; (void)out_size; (void)ws_size;
    const float* X     = (const float*)d_in[0];
    const float* state = (const float*)d_in[1];
    const float* Wxr   = (const float*)d_in[2];
    const float* Whr   = (const float*)d_in[3];
    const float* br    = (const float*)d_in[4];
    const float* Wxz   = (const float*)d_in[5];
    const float* Whz   = (const float*)d_in[6];
    const float* bz    = (const float*)d_in[7];
    const float* Wxh   = (const float*)d_in[8];
    const float* Whh   = (const float*)d_in[9];
    const float* bh    = (const float*)d_in[10];
    float* out = (float*)d_out;
    char* ws = (char*)d_ws;

    u16* XR   = (u16*)(ws + OFF_XR);
    u16* XZ   = (u16*)(ws + OFF_XZ);
    u16* XH   = (u16*)(ws + OFF_XH);
    u16* WXRT = (u16*)(ws + OFF_WXRT);
    u16* WXZT = (u16*)(ws + OFF_WXZT);
    u16* WXHT = (u16*)(ws + OFF_WXHT);
    u16* WHRT = (u16*)(ws + OFF_WHRT);
    u16* WHZT = (u16*)(ws + OFF_WHZT);
    u16* WHHT = (u16*)(ws + OFF_WHHT);
    u16* HBF  = (u16*)(ws + OFF_HBF);
    u16* RHBF = (u16*)(ws + OFF_RHBF);
    unsigned* BAR = (unsigned*)(ws + OFF_BAR);

    hipMemsetAsync(BAR, 0, BAR_BYTES, stream);

    transpose_cvt<<<dim3(32, 32, 6), 256, 0, stream>>>(
        Wxr, Wxz, Wxh, Whr, Whz, Whh,
        WXRT, WXZT, WXHT, WHRT, WHZT, WHHT);

    proj_gemm<<<dim3(8, 256, 3), 256, 0, stream>>>(
        X, WXRT, WXZT, WXHT, br, bz, bh, XR, XZ, XH);

    gru_rec<<<dim3(NBLK), 256, 0, stream>>>(
        XR, XZ, XH, WHRT, WHZT, WHHT, state,
        HBF, RHBF, BAR, out);
}

// Round 6
// 7153.073 us; speedup vs baseline: 1.7676x; 1.0533x over previous
//
#include <hip/hip_runtime.h>
#include <cmath>

typedef unsigned short u16;
typedef unsigned long long u64;
typedef __attribute__((ext_vector_type(4))) float f32x4;
typedef __attribute__((ext_vector_type(8))) __bf16 bf16x8;
typedef unsigned short u16x4 __attribute__((ext_vector_type(4)));
typedef unsigned short u16x8 __attribute__((ext_vector_type(8)));

#define T_STEPS 512
#define NBLK 64
#define FINAL_OFF 33554432u  // 512*64*1024

// ---------------- workspace layout (bytes) ----------------
#define OFF_XR   0ull
#define OFF_XZ   (OFF_XR + 67108864ull)     // 512*64*1024 * 2B each
#define OFF_XH   (OFF_XZ + 67108864ull)
#define OFF_WXRT (OFF_XH + 67108864ull)     // 1024*1024*2B each
#define OFF_WXZT (OFF_WXRT + 2097152ull)
#define OFF_WXHT (OFF_WXZT + 2097152ull)
#define OFF_WHRT (OFF_WXHT + 2097152ull)
#define OFF_WHZT (OFF_WHRT + 2097152ull)
#define OFF_WHHT (OFF_WHZT + 2097152ull)
#define OFF_HBF  (OFF_WHHT + 2097152ull)    // 64*1024 bf16 (cross-block, coherent)
#define OFF_RHBF (OFF_HBF + 131072ull)      // 64*1024 bf16 (cross-block, coherent)
#define OFF_HF32 (OFF_RHBF + 131072ull)     // (unused this version)
#define OFF_BAR  (OFF_HF32 + 262144ull)     // 256 per-WAVE flags, 128B apart (32KB)
#define BAR_BYTES 65600ull

// ---------------- helpers ----------------
__device__ __forceinline__ u16 f2bf(float f) {
    unsigned u = __builtin_bit_cast(unsigned, f);
    unsigned r = (u + 0x7FFFu + ((u >> 16) & 1u)) >> 16;
    return (u16)r;
}
__device__ __forceinline__ float bf2f(u16 h) {
    unsigned u = ((unsigned)h) << 16;
    return __builtin_bit_cast(float, u);
}
#define MFMA16 __builtin_amdgcn_mfma_f32_16x16x32_bf16

// coherent (agent-scope) atomic accesses: flags + cross-block data stores.
__device__ __forceinline__ void sta16(u16* p, u16 v) {
    __hip_atomic_store(p, v, __ATOMIC_RELAXED, __HIP_MEMORY_SCOPE_AGENT);
}
__device__ __forceinline__ void sta32(unsigned* p, unsigned v) {
    __hip_atomic_store(p, v, __ATOMIC_RELAXED, __HIP_MEMORY_SCOPE_AGENT);
}
__device__ __forceinline__ unsigned lda32(const unsigned* p) {
    return __hip_atomic_load(p, __ATOMIC_RELAXED, __HIP_MEMORY_SCOPE_AGENT);
}

// Raw coherent 16B load (sc0|sc1): same visibility as relaxed agent atomic,
// fire-and-forget issue; completion claimed by explicit vmcnt(0)+sched_barrier.
#define LD_A4(dst, vo, base)                                          \
    asm volatile("global_load_dwordx4 %0, %1, %2 sc0 sc1"             \
                 : "=v"(dst) : "v"(vo), "s"(base))

#define FLAG_STRIDE 32u  // 32 u32 = 128 bytes per flag

// ---------------- phase 0: transpose + fp32->bf16 convert, [K][N] -> [N][K] ----------------
__global__ __launch_bounds__(256) void transpose_cvt(
    const float* __restrict__ W0, const float* __restrict__ W1, const float* __restrict__ W2,
    const float* __restrict__ W3, const float* __restrict__ W4, const float* __restrict__ W5,
    u16* __restrict__ D0, u16* __restrict__ D1, u16* __restrict__ D2,
    u16* __restrict__ D3, u16* __restrict__ D4, u16* __restrict__ D5)
{
    const float* S[6] = {W0, W1, W2, W3, W4, W5};
    u16* D[6] = {D0, D1, D2, D3, D4, D5};
    int z = blockIdx.z;
    const float* W = S[z];
    u16* Dt = D[z];
    __shared__ float tile[32][33];
    int bx = blockIdx.x * 32, by = blockIdx.y * 32;
    int tx = threadIdx.x & 31, ty = threadIdx.x >> 5;
    for (int i = ty; i < 32; i += 8)
        tile[i][tx] = W[(size_t)(by + i) * 1024 + bx + tx];
    __syncthreads();
    for (int i = ty; i < 32; i += 8)
        Dt[(size_t)(bx + i) * 1024 + by + tx] = f2bf(tile[tx][i]);
}

// ---------------- phase 1: X @ Wx* + b -> bf16 projections ----------------
__global__ __launch_bounds__(256, 2) void proj_gemm(
    const float* __restrict__ X,
    const u16* __restrict__ Wt0, const u16* __restrict__ Wt1, const u16* __restrict__ Wt2,
    const float* __restrict__ b0, const float* __restrict__ b1, const float* __restrict__ b2,
    u16* __restrict__ P0, u16* __restrict__ P1, u16* __restrict__ P2)
{
    int z = blockIdx.z;
    const u16* Wt = (z == 0) ? Wt0 : (z == 1) ? Wt1 : Wt2;
    const float* bias = (z == 0) ? b0 : (z == 1) ? b1 : b2;
    u16* P = (z == 0) ? P0 : (z == 1) ? P1 : P2;

    __shared__ u16 Asm[128][72];
    __shared__ u16 Bsm[128][72];

    int tid = threadIdx.x, lane = tid & 63, w = tid >> 6;
    int m0 = blockIdx.y * 128, n0 = blockIdx.x * 128;
    int mw = (w >> 1) * 64, nw = (w & 1) * 64;
    int l15 = lane & 15, lq = lane >> 4;

    f32x4 zero = {0.f, 0.f, 0.f, 0.f};
    f32x4 acc[4][4];
    #pragma unroll
    for (int mi = 0; mi < 4; ++mi)
        #pragma unroll
        for (int nj = 0; nj < 4; ++nj) acc[mi][nj] = zero;

    for (int k0 = 0; k0 < 1024; k0 += 64) {
        #pragma unroll
        for (int i = 0; i < 8; ++i) {
            int flat = i * 256 + tid;
            int r = flat >> 4, c4 = flat & 15;
            float4 v = *(const float4*)(X + (size_t)(m0 + r) * 1024 + k0 + c4 * 4);
            u16x4 pk = {f2bf(v.x), f2bf(v.y), f2bf(v.z), f2bf(v.w)};
            *(u16x4*)&Asm[r][c4 * 4] = pk;
        }
        #pragma unroll
        for (int i = 0; i < 4; ++i) {
            int flat = i * 256 + tid;
            int n = flat >> 3, seg = flat & 7;
            *(u16x8*)&Bsm[n][seg * 8] = *(const u16x8*)(Wt + (size_t)(n0 + n) * 1024 + k0 + seg * 8);
        }
        __syncthreads();
        #pragma unroll
        for (int kk = 0; kk < 2; ++kk) {
            bf16x8 af[4], bg[4];
            #pragma unroll
            for (int mi = 0; mi < 4; ++mi)
                af[mi] = *(const bf16x8*)&Asm[mw + mi * 16 + l15][kk * 32 + lq * 8];
            #pragma unroll
            for (int nj = 0; nj < 4; ++nj)
                bg[nj] = *(const bf16x8*)&Bsm[nw + nj * 16 + l15][kk * 32 + lq * 8];
            #pragma unroll
            for (int mi = 0; mi < 4; ++mi)
                #pragma unroll
                for (int nj = 0; nj < 4; ++nj)
                    acc[mi][nj] = MFMA16(af[mi], bg[nj], acc[mi][nj], 0, 0, 0);
        }
        __syncthreads();
    }
    #pragma unroll
    for (int mi = 0; mi < 4; ++mi)
        #pragma unroll
        for (int nj = 0; nj < 4; ++nj)
            #pragma unroll
            for (int r = 0; r < 4; ++r) {
                int m = m0 + mw + mi * 16 + lq * 4 + r;
                int n = n0 + nw + nj * 16 + l15;
                float v = acc[mi][nj][r] + bias[n];
                P[(size_t)m * 1024 + n] = f2bf(v);
            }
}

// ---------------- phase 2: persistent recurrent kernel, PER-WAVE dataflow ----------------
// 64 blocks x 4 waves. Wave (b, mi) owns output tile rows [16mi,16mi+16) x
// cols [16b,16b+16). True dependence is per-wave: consumer wave mi reads only
// rows [16mi,..) of hbf/rhbf, which are produced exactly by wave mi of every
// block. So flags are per-WAVE (flag[b][mi], 256 flags): each wave publishes
// its own monotone counter after its own vmcnt(0) drain -- NO __syncthreads
// anywhere in the loop (Wsm is read-only after the init barrier; all other
// state is per-thread). Consumer wave mi gathers the 64 wave-mi flags (lane
// l -> flag[l][mi]) + ballot; per-k-pair gating with per-wave rotation.
// Protocol: init->1; stage1(t)->2t+2; stage2(t)->2t+3. Stage1 consumes hbf
// gated >=2t+1; stage2 consumes rhbf gated >=2t+2. flag>=N implies that
// wave's pre-N loads AND stores drained => WAR-safe on single-buffered
// hbf/rhbf (a wave reaches its epilogue only after polling all 64 peer
// flags, proving all peers finished reading what it overwrites).
__global__ __launch_bounds__(256, 1) void gru_rec(
    const u16* __restrict__ XR, const u16* __restrict__ XZ, const u16* __restrict__ XH,
    const u16* __restrict__ Whrt, const u16* __restrict__ Whzt, const u16* __restrict__ Whht,
    const float* __restrict__ state,
    u16* __restrict__ hbf, u16* __restrict__ rhbf,
    unsigned* __restrict__ bar, float* __restrict__ out)
{
    __shared__ u16 Wsm[48 * 1024];  // rows 0-15 Whr, 16-31 Whz, 32-47 Whh (96 KB)

    const int b = blockIdx.x, tid = threadIdx.x;
    const int lane = tid & 63, mi = tid >> 6;
    const int n15 = lane & 15, q = lane >> 4;
    const int k7 = n15 & 7;
    const int colg = 16 * b + n15;
    const int rowA = mi * 16 + n15;
    const int rot = (((b >> 1) + ((b & 1) << 4)) + mi * 8) & 31;  // per-wave start pair
    const u64 own_bit = 1ull << b;

    // fill LDS weight slices (swizzled 16B chunks: phys = chunk ^ (row&7))
    {
        int r0 = tid >> 3, seg = tid & 7;
        #pragma unroll
        for (int pass = 0; pass < 2; ++pass) {
            int row = pass * 32 + r0;
            if (row < 48) {
                const u16* src = (row < 16) ? (Whrt + (size_t)(16 * b + row) * 1024)
                               : (row < 32) ? (Whzt + (size_t)(16 * b + row - 16) * 1024)
                                            : (Whht + (size_t)(16 * b + row - 32) * 1024);
                #pragma unroll
                for (int v = 0; v < 16; ++v) {
                    int chunk = seg * 16 + v;
                    int phys = chunk ^ (row & 7);
                    *(u16x8*)&Wsm[row * 1024 + phys * 8] = *(const u16x8*)(src + chunk * 8);
                }
            }
        }
    }
    // init h: each wave stores its own tile (rows [16mi,..) x cols [16b,..))
    f32x4 hcar;
    #pragma unroll
    for (int r = 0; r < 4; ++r) {
        int idx = (mi * 16 + q * 4 + r) * 1024 + colg;
        float v = state[idx];
        hcar[r] = v;
        sta16(hbf + idx, f2bf(v));
    }
    // publish init (flag = 1), per-wave; then one barrier for Wsm visibility
    asm volatile("s_waitcnt vmcnt(0)" ::: "memory");
    if (lane == 0) sta32(bar + (unsigned)((b << 2) | mi) * FLAG_STRIDE, 1u);
    __syncthreads();  // Wsm ready for all 4 waves; last sync in the kernel

    const u64 hb64 = (u64)hbf;
    const u64 rb64 = (u64)rhbf;
    const unsigned vbA = (unsigned)(rowA * 2048 + q * 16);  // A-fragment byte base
    // lane l -> block l's wave-mi flag
    const unsigned* fp = bar + (unsigned)((lane << 2) | mi) * FLAG_STRIDE;
    unsigned* myflag = bar + (unsigned)((b << 2) | mi) * FLAG_STRIDE;

    for (int t = 0; t < T_STEPS; ++t) {
        f32x4 zreg;
        // ---------------- stage 1: R,Z; write rhbf = R*h ----------------
        {
            u16 xr16[4], xz16[4];
            #pragma unroll
            for (int r = 0; r < 4; ++r) {
                size_t xoff = (size_t)t * 65536 + (mi * 16 + q * 4 + r) * 1024 + colg;
                xr16[r] = XR[xoff];
                xz16[r] = XZ[xoff];
            }
            // dataflow consume: issue A-load for each k-pair as its producers arrive
            f32x4 a[32];
            const unsigned T1 = 2u * t + 1u;
            u64 rdy = __ballot(lda32(fp) >= T1) | own_bit;  // fast path: one gather
            #pragma unroll
            for (int i = 0; i < 32; ++i) {
                int kb = (i + rot) & 31;
                u64 need = 3ull << (2 * kb);
                while ((rdy & need) != need) {
                    __builtin_amdgcn_s_sleep(1);
                    rdy = __ballot(lda32(fp) >= T1) | own_bit;
                }
                LD_A4(a[i], vbA + kb * 64, hb64);
            }
            asm volatile("s_waitcnt vmcnt(0)" ::: "memory");
            __builtin_amdgcn_sched_barrier(0);

            f32x4 aRa = {0,0,0,0}, aRb = {0,0,0,0}, aZa = {0,0,0,0}, aZb = {0,0,0,0};
            #pragma unroll
            for (int i = 0; i < 32; ++i) {
                int kb = (i + rot) & 31;
                bf16x8 av = __builtin_bit_cast(bf16x8, a[i]);
                int ph = ((kb * 4 + q) ^ k7) * 8;
                bf16x8 br = *(const bf16x8*)&Wsm[n15 * 1024 + ph];
                bf16x8 bz = *(const bf16x8*)&Wsm[(16 + n15) * 1024 + ph];
                if (i & 1) { aRb = MFMA16(av, br, aRb, 0, 0, 0); aZb = MFMA16(av, bz, aZb, 0, 0, 0); }
                else       { aRa = MFMA16(av, br, aRa, 0, 0, 0); aZa = MFMA16(av, bz, aZa, 0, 0, 0); }
            }
            f32x4 accR = aRa + aRb, accZ = aZa + aZb;
            #pragma unroll
            for (int r = 0; r < 4; ++r) {
                int idx = (mi * 16 + q * 4 + r) * 1024 + colg;
                float rpre = accR[r] + bf2f(xr16[r]);
                float zpre = accZ[r] + bf2f(xz16[r]);
                float R = 1.f / (1.f + __expf(-rpre));
                zreg[r] = 1.f / (1.f + __expf(-zpre));
                sta16(rhbf + idx, f2bf(R * hcar[r]));
            }
            // publish stage 1 (flag = 2t+2): per-wave drain + own flag store
            asm volatile("s_waitcnt vmcnt(0)" ::: "memory");
            if (lane == 0) sta32(myflag, 2u * t + 2u);
        }
        // ---------------- stage 2: Hhat = tanh(Xh + (R*h)@Whh); blend ----------------
        {
            u16 xh16[4];
            #pragma unroll
            for (int r = 0; r < 4; ++r) {
                size_t xoff = (size_t)t * 65536 + (mi * 16 + q * 4 + r) * 1024 + colg;
                xh16[r] = XH[xoff];
            }
            f32x4 a[32];
            const unsigned T2 = 2u * t + 2u;
            u64 rdy = __ballot(lda32(fp) >= T2) | own_bit;  // fast path: one gather
            #pragma unroll
            for (int i = 0; i < 32; ++i) {
                int kb = (i + rot) & 31;
                u64 need = 3ull << (2 * kb);
                while ((rdy & need) != need) {
                    __builtin_amdgcn_s_sleep(1);
                    rdy = __ballot(lda32(fp) >= T2) | own_bit;
                }
                LD_A4(a[i], vbA + kb * 64, rb64);
            }
            asm volatile("s_waitcnt vmcnt(0)" ::: "memory");
            __builtin_amdgcn_sched_barrier(0);

            f32x4 ca = {0,0,0,0}, cb = {0,0,0,0};
            #pragma unroll
            for (int i = 0; i < 32; ++i) {
                int kb = (i + rot) & 31;
                bf16x8 av = __builtin_bit_cast(bf16x8, a[i]);
                int ph = ((kb * 4 + q) ^ k7) * 8;
                bf16x8 bh = *(const bf16x8*)&Wsm[(32 + n15) * 1024 + ph];
                if (i & 1) cb = MFMA16(av, bh, cb, 0, 0, 0);
                else       ca = MFMA16(av, bh, ca, 0, 0, 0);
            }
            f32x4 acc = ca + cb;
            float hn4[4];
            #pragma unroll
            for (int r = 0; r < 4; ++r) {
                int idx = (mi * 16 + q * 4 + r) * 1024 + colg;
                float pre = acc[r] + bf2f(xh16[r]);
                float ax = fabsf(pre);
                float e = __expf(-2.f * ax);
                float th = (1.f - e) / (1.f + e);
                float hh = (pre < 0.f) ? -th : th;
                float hn = zreg[r] * hcar[r] + (1.f - zreg[r]) * hh;
                hn4[r] = hn;
                hcar[r] = hn;
                sta16(hbf + idx, f2bf(hn));     // shared (coherent)
            }
            if (t != T_STEPS - 1) {
                // publish stage 2 (flag = 2t+3) BEFORE the out stores (out is
                // write-once, consumed only at kernel end; keeps HBM stores
                // off the publish critical path)
                asm volatile("s_waitcnt vmcnt(0)" ::: "memory");
                if (lane == 0) sta32(myflag, 2u * t + 3u);
            }
            #pragma unroll
            for (int r = 0; r < 4; ++r) {
                int idx = (mi * 16 + q * 4 + r) * 1024 + colg;
                size_t xoff = (size_t)t * 65536 + idx;
                out[xoff] = hn4[r];
                if (t == T_STEPS - 1) out[FINAL_OFF + idx] = hn4[r];
            }
        }
    }
}

// ---------------- launch ----------------
extern "C" void kernel_launch(void* const* d_in, const int* in_sizes, int n_in,
                              void* d_out, int out_size, void* d_ws, size_t ws_size,
                              hipStream_t stream) {
    (void)in_sizes; (void)n_in; (void)out_size; (void)ws_size;
    const float* X     = (const float*)d_in[0];
    const float* state = (const float*)d_in[1];
    const float* Wxr   = (const float*)d_in[2];
    const float* Whr   = (const float*)d_in[3];
    const float* br    = (const float*)d_in[4];
    const float* Wxz   = (const float*)d_in[5];
    const float* Whz   = (const float*)d_in[6];
    const float* bz    = (const float*)d_in[7];
    const float* Wxh   = (const float*)d_in[8];
    const float* Whh   = (const float*)d_in[9];
    const float* bh    = (const float*)d_in[10];
    float* out = (float*)d_out;
    char* ws = (char*)d_ws;

    u16* XR   = (u16*)(ws + OFF_XR);
    u16* XZ   = (u16*)(ws + OFF_XZ);
    u16* XH   = (u16*)(ws + OFF_XH);
    u16* WXRT = (u16*)(ws + OFF_WXRT);
    u16* WXZT = (u16*)(ws + OFF_WXZT);
    u16* WXHT = (u16*)(ws + OFF_WXHT);
    u16* WHRT = (u16*)(ws + OFF_WHRT);
    u16* WHZT = (u16*)(ws + OFF_WHZT);
    u16* WHHT = (u16*)(ws + OFF_WHHT);
    u16* HBF  = (u16*)(ws + OFF_HBF);
    u16* RHBF = (u16*)(ws + OFF_RHBF);
    unsigned* BAR = (unsigned*)(ws + OFF_BAR);

    hipMemsetAsync(BAR, 0, BAR_BYTES, stream);

    transpose_cvt<<<dim3(32, 32, 6), 256, 0, stream>>>(
        Wxr, Wxz, Wxh, Whr, Whz, Whh,
        WXRT, WXZT, WXHT, WHRT, WHZT, WHHT);

    proj_gemm<<<dim3(8, 256, 3), 256, 0, stream>>>(
        X, WXRT, WXZT, WXHT, br, bz, bh, XR, XZ, XH);

    gru_rec<<<dim3(NBLK), 256, 0, stream>>>(
        XR, XZ, XH, WHRT, WHZT, WHHT, state,
        HBF, RHBF, BAR, out);
}